// Round 8
// baseline (473.551 us; speedup 1.0000x reference)
//
#include <hip/hip_runtime.h>
#include <hip/hip_bf16.h>

// ---------------------------------------------------------------------------
// GAT (2-layer, PyG-style) on MI355X.
// R8: gemm grids de-quantized (gemm1 BM=64 -> 782 blk = 3/CU; gemm2 BM=64/
//     NT=64 -> 782 single-wave blk vs 0.77 blk/CU), agg_l2 -> 16 edges/wave,
//     packed f32x2 accumulation (v_pk_fma_f32 target) in both agg kernels.
//     Keeps: hierarchical scan, direct-eix hist/fill, folded weight prep,
//     global-per-head-max rescale-free softmax, 3-stage gather pipeline.
// ---------------------------------------------------------------------------

typedef __attribute__((ext_vector_type(8)))  __bf16          bf16x8;
typedef __attribute__((ext_vector_type(8)))  unsigned short  ushort8;
typedef __attribute__((ext_vector_type(16))) float           f32x16;
typedef __attribute__((ext_vector_type(2)))  float           f32x2;

#define NEG_SLOPE 0.2f
#define EPS_GAT 1e-16f

union U8 { ushort8 v; unsigned u[4]; };

static __device__ __forceinline__ float lrelu(float x) {
    return x > 0.0f ? x : NEG_SLOPE * x;
}
static __device__ __forceinline__ unsigned short f2bf(float f) {
    unsigned u = __float_as_uint(f);
    return (unsigned short)((u + 0x7fffu + ((u >> 16) & 1u)) >> 16);
}
static __device__ __forceinline__ float bf2f(unsigned short v) {
    return __uint_as_float(((unsigned)v) << 16);
}
// two packed bf16 (one dword) -> f32 pair (2 VALU ops, no shifts per element)
static __device__ __forceinline__ f32x2 cvt2(unsigned u) {
    f32x2 r;
    r.x = __uint_as_float(u << 16);
    r.y = __uint_as_float(u & 0xffff0000u);
    return r;
}
// ordered-uint encoding for float atomicMax; enc(x)>0 for finite x, so
// memset-0 init acts as -inf.
static __device__ __forceinline__ unsigned encf(float x) {
    unsigned u = __float_as_uint(x);
    return (u >> 31) ? ~u : (u | 0x80000000u);
}
static __device__ __forceinline__ float decf(unsigned e) {
    unsigned u = (e >> 31) ? (e & 0x7fffffffu) : ~e;
    return __uint_as_float(u);
}

// --------------- histogram (direct eix, per-block dtype detect) ------------
__global__ void k_hist_w(const void* __restrict__ eix, int* __restrict__ counts,
                         int E, int EB,
                         const float* __restrict__ W1, const float* __restrict__ W2,
                         unsigned short* __restrict__ w1t, unsigned short* __restrict__ w2t) {
    int b = blockIdx.x;
    if (b < EB) {
        int i = b * 256 + threadIdx.x;
        unsigned w = ((const unsigned*)eix)[2 * min(i, E - 1) + 1];
        bool is64 = (__syncthreads_or((int)(w != 0u)) == 0);
        if (i < E) {
            int d = is64 ? (int)((const long long*)eix)[E + i]
                         : ((const int*)eix)[E + i];
            atomicAdd(&counts[d], 1);
        }
    } else {
        int t = (b - EB) * 256 + threadIdx.x;
        if (t < 512 * 256) {
            int k = t >> 8, m = t & 255;
            w1t[m * 512 + k] = f2bf(W1[t]);
        } else {
            int u = t - 512 * 256;
            if (u < 256 * 64) {
                int k = u >> 6, m = u & 63;
                w2t[m * 256 + k] = f2bf(W2[u]);
            }
        }
    }
}

// -------------------- hierarchical CSR scan (3 kernels) --------------------
__global__ void k_scan1(const int* __restrict__ counts, int* __restrict__ rowp,
                        int* __restrict__ bsum, int N) {
    __shared__ int s[256];
    int t = threadIdx.x, i = blockIdx.x * 256 + t;
    int v = (i < N) ? counts[i] : 0;
    s[t] = v;
    __syncthreads();
    for (int off = 1; off < 256; off <<= 1) {
        int u = (t >= off) ? s[t - off] : 0;
        __syncthreads();
        s[t] += u;
        __syncthreads();
    }
    if (i < N) rowp[i] = s[t] - v;          // exclusive within block
    if (t == 255) bsum[blockIdx.x] = s[255];
}

__global__ void k_scan2(const int* __restrict__ bsum, int* __restrict__ boff,
                        int* __restrict__ rowp_last, int NB) {
    __shared__ int s[256];
    int t = threadIdx.x;
    int v = (t < NB) ? bsum[t] : 0;
    s[t] = v;
    __syncthreads();
    for (int off = 1; off < 256; off <<= 1) {
        int u = (t >= off) ? s[t - off] : 0;
        __syncthreads();
        s[t] += u;
        __syncthreads();
    }
    if (t < NB) boff[t] = s[t] - v;
    if (t == 255) *rowp_last = s[255];      // == E
}

__global__ void k_scan3(int* __restrict__ rowp, int* __restrict__ cursor,
                        const int* __restrict__ boff, int N) {
    int i = blockIdx.x * 256 + threadIdx.x;
    if (i < N) {
        int r = rowp[i] + boff[blockIdx.x];
        rowp[i] = r;
        cursor[i] = r;
    }
}

// ------------------------ fill (direct eix reads) --------------------------
__global__ void k_fill(const void* __restrict__ eix, int* __restrict__ cursor,
                       int* __restrict__ ssrc, int E) {
    int i = blockIdx.x * 256 + threadIdx.x;
    unsigned w = ((const unsigned*)eix)[2 * min(i, E - 1) + 1];
    bool is64 = (__syncthreads_or((int)(w != 0u)) == 0);
    if (i >= E) return;
    int s, d;
    if (is64) {
        s = (int)((const long long*)eix)[i];
        d = (int)((const long long*)eix)[E + i];
    } else {
        s = ((const int*)eix)[i];
        d = ((const int*)eix)[E + i];
    }
    int pos = atomicAdd(&cursor[d], 1);
    ssrc[pos] = s;
}

// ------------------------------- bf16 GEMM ---------------------------------
template <int BM, int BN, int NT, bool AF32, bool OUTBF>
__global__ __launch_bounds__(NT) void k_gemm(const void* __restrict__ Ain,
                                             const unsigned short* __restrict__ Bt,
                                             void* __restrict__ Cout, int Nrows, int K) {
    constexpr int LD = 40;
    __shared__ __align__(16) unsigned short As[BM * LD];
    __shared__ __align__(16) unsigned short Bs[BN * LD];
    const int tid = threadIdx.x;
    const int blockRow = blockIdx.x * BM;
    const int wave = tid >> 6, lane = tid & 63;
    constexpr int WR = BM / 64;
    const int wr = wave % WR, wc = wave / WR;
    const int m = lane & 31;
    const int ksel = (lane >> 5) * 8;

    f32x16 acc00{}, acc01{}, acc10{}, acc11{};

    for (int kt = 0; kt < K; kt += 32) {
        if constexpr (AF32) {
            const float* A = (const float*)Ain;
            for (int idx = tid; idx < BM * 4; idx += NT) {
                int r = idx >> 2, kc = (idx & 3) * 8;
                int grow = blockRow + r;
                union { ushort8 u; __hip_bfloat162 h[4]; } cv;
                if (grow < Nrows) {
                    const float* ap = A + (size_t)grow * K + kt + kc;
                    float4 x0 = *(const float4*)ap;
                    float4 x1 = *(const float4*)(ap + 4);
                    cv.h[0] = __float22bfloat162_rn(make_float2(x0.x, x0.y));
                    cv.h[1] = __float22bfloat162_rn(make_float2(x0.z, x0.w));
                    cv.h[2] = __float22bfloat162_rn(make_float2(x1.x, x1.y));
                    cv.h[3] = __float22bfloat162_rn(make_float2(x1.z, x1.w));
                } else {
                    cv.u = ushort8{};
                }
                *(ushort8*)&As[r * LD + kc] = cv.u;
            }
        } else {
            const unsigned short* A = (const unsigned short*)Ain;
            for (int idx = tid; idx < BM * 4; idx += NT) {
                int r = idx >> 2, kc = (idx & 3) * 8;
                int grow = blockRow + r;
                ushort8 o{};
                if (grow < Nrows) o = *(const ushort8*)(A + (size_t)grow * K + kt + kc);
                *(ushort8*)&As[r * LD + kc] = o;
            }
        }
        for (int idx = tid; idx < BN * 4; idx += NT) {
            int r = idx >> 2, kc = (idx & 3) * 8;
            *(ushort8*)&Bs[r * LD + kc] = *(const ushort8*)(Bt + (size_t)r * K + kt + kc);
        }
        __syncthreads();

        #pragma unroll
        for (int kk = 0; kk < 32; kk += 16) {
            bf16x8 a0 = *(const bf16x8*)&As[(wr * 64 +      m) * LD + kk + ksel];
            bf16x8 a1 = *(const bf16x8*)&As[(wr * 64 + 32 + m) * LD + kk + ksel];
            bf16x8 b0 = *(const bf16x8*)&Bs[(wc * 64 +      m) * LD + kk + ksel];
            bf16x8 b1 = *(const bf16x8*)&Bs[(wc * 64 + 32 + m) * LD + kk + ksel];
            acc00 = __builtin_amdgcn_mfma_f32_32x32x16_bf16(a0, b0, acc00, 0, 0, 0);
            acc01 = __builtin_amdgcn_mfma_f32_32x32x16_bf16(a0, b1, acc01, 0, 0, 0);
            acc10 = __builtin_amdgcn_mfma_f32_32x32x16_bf16(a1, b0, acc10, 0, 0, 0);
            acc11 = __builtin_amdgcn_mfma_f32_32x32x16_bf16(a1, b1, acc11, 0, 0, 0);
        }
        __syncthreads();
    }

    const int dcol = wc * 64 + (lane & 31);
    const int dquad = 4 * (lane >> 5);
    auto store_tile = [&](const f32x16& a, int rt, int ct) {
        #pragma unroll
        for (int r = 0; r < 16; ++r) {
            int row = blockRow + wr * 64 + rt * 32 + (r & 3) + 8 * (r >> 2) + dquad;
            if (row < Nrows) {
                size_t off = (size_t)row * BN + dcol + ct * 32;
                if constexpr (OUTBF) ((unsigned short*)Cout)[off] = f2bf(a[r]);
                else                 ((float*)Cout)[off] = a[r];
            }
        }
    };
    store_tile(acc00, 0, 0); store_tile(acc01, 0, 1);
    store_tile(acc10, 1, 0); store_tile(acc11, 1, 1);
}

// ----------- attention logits + global head max (atomicMax enc) ------------
__global__ void k_alpha(const unsigned short* __restrict__ xw, const float* __restrict__ a_s,
                        const float* __restrict__ a_d, float* __restrict__ os,
                        float* __restrict__ od, unsigned* __restrict__ Menc,
                        int NH, int H, int C) {
    __shared__ float red[256];
    int t = blockIdx.x * 256 + threadIdx.x;
    float s = -1e30f, d = 0.f;
    if (t < NH) {
        int n = t / H, h = t - n * H;
        const unsigned short* row = xw + (size_t)n * H * C + h * C;
        s = 0.f;
        for (int c = 0; c < C; c += 8) {
            ushort8 v = *(const ushort8*)(row + c);
            #pragma unroll
            for (int q = 0; q < 8; ++q) {
                float f = bf2f(v[q]);
                s += f * a_s[h * C + c + q];
                d += f * a_d[h * C + c + q];
            }
        }
        os[t] = s; od[t] = d;
    }
    red[threadIdx.x] = s;
    __syncthreads();
    for (int off = 128; off >= H; off >>= 1) {
        if (threadIdx.x < off) red[threadIdx.x] = fmaxf(red[threadIdx.x], red[threadIdx.x + off]);
        __syncthreads();
    }
    if ((int)threadIdx.x < H) atomicMax(&Menc[threadIdx.x], encf(red[threadIdx.x]));
}

// ---- layer 1: 4 edges/wave, 3-stage pipeline, packed f32x2 accumulate -----
// g = lane>>4 picks edge of quad; q = lane&15 holds features [q*16, q*16+16)
__global__ __launch_bounds__(256) void k_agg_l1(
        const unsigned short* __restrict__ xw1, const float* __restrict__ asrc,
        const float* __restrict__ adst, const unsigned* __restrict__ Menc,
        const float* __restrict__ b1, const int* __restrict__ rp,
        const int* __restrict__ ssrc, unsigned short* __restrict__ hbf, int N) {
    int wid = (blockIdx.x * 256 + threadIdx.x) >> 6;
    if (wid >= N) return;
    int lane = threadIdx.x & 63;
    int g  = lane >> 4;
    int q  = lane & 15;
    int f0 = q * 16;
    int h  = q >> 1;
    int ih = wid * 8 + h;
    float ad = adst[ih];
    float m  = lrelu(decf(Menc[h]) + ad);   // >= all edge logits (lrelu monotone)
    f32x2 acc2[8];
    float s;
    {   // self loop counted on group 0 only
        float w = (g == 0) ? __expf(lrelu(asrc[ih] + ad) - m) : 0.0f;
        f32x2 w2 = {w, w};
        const unsigned short* pr = xw1 + (size_t)wid * 256 + f0;
        U8 lo, hi;
        lo.v = *(const ushort8*)pr;
        hi.v = *(const ushort8*)(pr + 8);
        s = w;
        #pragma unroll
        for (int i = 0; i < 4; ++i) {
            acc2[i]     = w2 * cvt2(lo.u[i]);
            acc2[4 + i] = w2 * cvt2(hi.u[i]);
        }
    }
    int e0 = rp[wid], e1 = rp[wid + 1];
    if (e0 < e1) {
        int eA = e0;
        bool vA = eA + g < e1;
        int jA = ssrc[min(eA + g, e1 - 1)];
        float asA = asrc[jA * 8 + h];
        const unsigned short* pA = xw1 + (size_t)jA * 256 + f0;
        U8 loA, hiA;
        loA.v = *(const ushort8*)pA;
        hiA.v = *(const ushort8*)(pA + 8);
        int eB = e0 + 4;
        bool hasB = eB < e1;
        bool vB = false; int jB = 0;
        if (hasB) { vB = eB + g < e1; jB = ssrc[min(eB + g, e1 - 1)]; }
        int eC = e0 + 8;
        while (true) {
            bool hasC = eC < e1;
            bool vC = false; int jC = 0;
            if (hasC) { vC = eC + g < e1; jC = ssrc[min(eC + g, e1 - 1)]; }
            float asB = 0.f; U8 loB{}, hiB{};
            if (hasB) {
                asB = asrc[jB * 8 + h];
                const unsigned short* pB = xw1 + (size_t)jB * 256 + f0;
                loB.v = *(const ushort8*)pB;
                hiB.v = *(const ushort8*)(pB + 8);
            }
            float w = vA ? __expf(lrelu(asA + ad) - m) : 0.0f;
            f32x2 w2 = {w, w};
            s += w;
            #pragma unroll
            for (int i = 0; i < 4; ++i) {
                acc2[i]     += w2 * cvt2(loA.u[i]);
                acc2[4 + i] += w2 * cvt2(hiA.u[i]);
            }
            if (!hasB) break;
            vA = vB; asA = asB; loA = loB; hiA = hiB;
            jB = jC; vB = vC; hasB = hasC;
            eC += 4;
        }
    }
    // combine the 4 edge-groups (lane bits 4..5)
    s += __shfl_xor(s, 16, 64);
    s += __shfl_xor(s, 32, 64);
    #pragma unroll
    for (int i = 0; i < 8; ++i) {
        acc2[i].x += __shfl_xor(acc2[i].x, 16, 64);
        acc2[i].x += __shfl_xor(acc2[i].x, 32, 64);
        acc2[i].y += __shfl_xor(acc2[i].y, 16, 64);
        acc2[i].y += __shfl_xor(acc2[i].y, 32, 64);
    }
    float inv = 1.0f / (s + EPS_GAT);
    // group g writes features [f0 + g*4, f0 + g*4 + 4) = acc2[2g], acc2[2g+1]
    int fw = f0 + g * 4;
    float vv[4] = { acc2[2 * g].x, acc2[2 * g].y, acc2[2 * g + 1].x, acc2[2 * g + 1].y };
    ushort4 o;
    #pragma unroll
    for (int i = 0; i < 4; ++i) {
        float v = vv[i] * inv + b1[fw + i];
        v = v > 0.f ? v : expm1f(v);
        ((unsigned short*)&o)[i] = f2bf(v);
    }
    *(ushort4*)(hbf + (size_t)wid * 256 + fw) = o;
}

// ---- layer 2: 16 edges/wave, 3-stage pipeline + fused log_softmax ---------
// g = lane>>2 picks edge of 16; q = lane&3 holds classes [q*16, q*16+16)
__global__ __launch_bounds__(256) void k_agg_l2(
        const unsigned short* __restrict__ xw2, const float* __restrict__ asrc,
        const float* __restrict__ adst, const unsigned* __restrict__ Menc,
        const float* __restrict__ b2, const int* __restrict__ rp,
        const int* __restrict__ ssrc, float* __restrict__ out, int N) {
    int wid = (blockIdx.x * 256 + threadIdx.x) >> 6;
    if (wid >= N) return;
    int lane = threadIdx.x & 63;
    int g  = lane >> 2;
    int q  = lane & 3;
    int f0 = q * 16;
    float ad = adst[wid];
    float m = lrelu(decf(Menc[0]) + ad);
    f32x2 acc2[8];
    float s;
    {   // self loop counted on group 0 only
        float w = (g == 0) ? __expf(lrelu(asrc[wid] + ad) - m) : 0.0f;
        f32x2 w2 = {w, w};
        const unsigned short* pr = xw2 + (size_t)wid * 64 + f0;
        U8 lo, hi;
        lo.v = *(const ushort8*)pr;
        hi.v = *(const ushort8*)(pr + 8);
        s = w;
        #pragma unroll
        for (int i = 0; i < 4; ++i) {
            acc2[i]     = w2 * cvt2(lo.u[i]);
            acc2[4 + i] = w2 * cvt2(hi.u[i]);
        }
    }
    int e0 = rp[wid], e1 = rp[wid + 1];
    if (e0 < e1) {
        int eA = e0;
        bool vA = eA + g < e1;
        int jA = ssrc[min(eA + g, e1 - 1)];
        float asA = asrc[jA];
        const unsigned short* pA = xw2 + (size_t)jA * 64 + f0;
        U8 loA, hiA;
        loA.v = *(const ushort8*)pA;
        hiA.v = *(const ushort8*)(pA + 8);
        int eB = e0 + 16;
        bool hasB = eB < e1;
        bool vB = false; int jB = 0;
        if (hasB) { vB = eB + g < e1; jB = ssrc[min(eB + g, e1 - 1)]; }
        int eC = e0 + 32;
        while (true) {
            bool hasC = eC < e1;
            bool vC = false; int jC = 0;
            if (hasC) { vC = eC + g < e1; jC = ssrc[min(eC + g, e1 - 1)]; }
            float asB = 0.f; U8 loB{}, hiB{};
            if (hasB) {
                asB = asrc[jB];
                const unsigned short* pB = xw2 + (size_t)jB * 64 + f0;
                loB.v = *(const ushort8*)pB;
                hiB.v = *(const ushort8*)(pB + 8);
            }
            float w = vA ? __expf(lrelu(asA + ad) - m) : 0.0f;
            f32x2 w2 = {w, w};
            s += w;
            #pragma unroll
            for (int i = 0; i < 4; ++i) {
                acc2[i]     += w2 * cvt2(loA.u[i]);
                acc2[4 + i] += w2 * cvt2(hiA.u[i]);
            }
            if (!hasB) break;
            vA = vB; asA = asB; loA = loB; hiA = hiB;
            jB = jC; vB = vC; hasB = hasC;
            eC += 16;
        }
    }
    // reduce over the 16 edge-groups (lane bits 2..5)
    s += __shfl_xor(s, 4, 64);  s += __shfl_xor(s, 8, 64);
    s += __shfl_xor(s, 16, 64); s += __shfl_xor(s, 32, 64);
    #pragma unroll
    for (int i = 0; i < 8; ++i) {
        #pragma unroll
        for (int off = 4; off <= 32; off <<= 1) {
            acc2[i].x += __shfl_xor(acc2[i].x, off, 64);
            acc2[i].y += __shfl_xor(acc2[i].y, off, 64);
        }
    }
    float inv = 1.0f / (s + EPS_GAT);
    float val[16];
    float mx = -1e30f;
    #pragma unroll
    for (int i = 0; i < 16; ++i) {
        float a = (i & 1) ? acc2[i >> 1].y : acc2[i >> 1].x;
        val[i] = a * inv + b2[f0 + i];
        mx = fmaxf(mx, val[i]);
    }
    // class reduce across q lanes (bits 0..1)
    mx = fmaxf(mx, __shfl_xor(mx, 1, 64));
    mx = fmaxf(mx, __shfl_xor(mx, 2, 64));
    float sm = 0.f;
    #pragma unroll
    for (int i = 0; i < 16; ++i) sm += __expf(val[i] - mx);
    sm += __shfl_xor(sm, 1, 64);
    sm += __shfl_xor(sm, 2, 64);
    float lse = mx + logf(sm);
    if (g == 0) {
        #pragma unroll
        for (int i = 0; i < 16; i += 4) {
            float4 o = make_float4(val[i] - lse, val[i + 1] - lse,
                                   val[i + 2] - lse, val[i + 3] - lse);
            *(float4*)(out + (size_t)wid * 64 + f0 + i) = o;
        }
    }
}

// ------------------------------- launcher ----------------------------------
static inline int cdiv(int a, int b) { return (a + b - 1) / b; }

extern "C" void kernel_launch(void* const* d_in, const int* in_sizes, int n_in,
                              void* d_out, int out_size, void* d_ws, size_t ws_size,
                              hipStream_t stream) {
    const float* x   = (const float*)d_in[0];
    const void*  eix = d_in[1];
    const float* W1  = (const float*)d_in[2];
    const float* as1 = (const float*)d_in[3];
    const float* ad1 = (const float*)d_in[4];
    const float* b1  = (const float*)d_in[5];
    const float* W2  = (const float*)d_in[6];
    const float* as2 = (const float*)d_in[7];
    const float* ad2 = (const float*)d_in[8];
    const float* b2  = (const float*)d_in[9];
    float* out = (float*)d_out;

    const int N = in_sizes[0] / 512;
    const int E = in_sizes[1] / 2;
    const int EB = cdiv(E, 256);
    const int WB = cdiv(512 * 256 + 256 * 64, 256);
    const int NB = cdiv(N, 256);
    const int NB1 = cdiv(N * 8, 256);
    const int NB2 = cdiv(N, 256);
    (void)n_in; (void)out_size; (void)ws_size;

    char* base = (char*)d_ws;
    size_t o = 0;
    auto alloc = [&](size_t bytes) -> char* {
        o = (o + 255) & ~(size_t)255;
        char* p = base + o;
        o += bytes;
        return p;
    };
    unsigned short* xw1b  = (unsigned short*)alloc((size_t)N * 256 * 2);
    unsigned short* hbf   = (unsigned short*)alloc((size_t)N * 256 * 2);
    unsigned short* xw2b  = (unsigned short*)alloc((size_t)N * 64 * 2);
    float*          asrc1 = (float*)alloc((size_t)N * 8 * 4);
    float*          adst1 = (float*)alloc((size_t)N * 8 * 4);
    float*          asrc2 = (float*)alloc((size_t)N * 4);
    float*          adst2 = (float*)alloc((size_t)N * 4);
    // zero region: Menc + counts contiguous, one memset
    size_t zero_begin = (o + 255) & ~(size_t)255;
    unsigned*       Menc  = (unsigned*)alloc(16 * 4);   // [0..7]=L1 heads, [8]=L2
    int*            counts= (int*)alloc((size_t)N * 4);
    size_t zero_end = o;
    int*            cursor= (int*)alloc((size_t)N * 4);
    int*            rowp  = (int*)alloc((size_t)(N + 1) * 4);
    int*            bsum  = (int*)alloc(256 * 4);
    int*            boff  = (int*)alloc(256 * 4);
    unsigned short* w1t   = (unsigned short*)alloc(512 * 256 * 2);
    unsigned short* w2t   = (unsigned short*)alloc(256 * 64 * 2);
    int*            ssrc  = (int*)alloc((size_t)E * 4);

    hipMemsetAsync(base + zero_begin, 0, zero_end - zero_begin, stream);

    // CSR build + weight prep folded into histogram grid
    k_hist_w<<<EB + WB, 256, 0, stream>>>(eix, counts, E, EB, W1, W2, w1t, w2t);
    k_scan1<<<NB, 256, 0, stream>>>(counts, rowp, bsum, N);
    k_scan2<<<1, 256, 0, stream>>>(bsum, boff, rowp + N, NB);
    k_scan3<<<NB, 256, 0, stream>>>(rowp, cursor, boff, N);
    k_fill<<<EB, 256, 0, stream>>>(eix, cursor, ssrc, E);

    // layer 1
    k_gemm<64, 256, 256, true, true><<<cdiv(N, 64), 256, 0, stream>>>(x, w1t, xw1b, N, 512);
    k_alpha<<<NB1, 256, 0, stream>>>(xw1b, as1, ad1, asrc1, adst1, Menc, N * 8, 8, 32);
    k_agg_l1<<<cdiv(N * 64, 256), 256, 0, stream>>>(xw1b, asrc1, adst1, Menc, b1,
                                                    rowp, ssrc, hbf, N);
    // layer 2
    k_gemm<64, 64, 64, false, true><<<cdiv(N, 64), 64, 0, stream>>>(hbf, w2t, xw2b, N, 256);
    k_alpha<<<NB2, 256, 0, stream>>>(xw2b, as2, ad2, asrc2, adst2, Menc + 8, N, 1, 64);
    k_agg_l2<<<cdiv(N * 64, 256), 256, 0, stream>>>(xw2b, asrc2, adst2, Menc + 8, b2,
                                                    rowp, ssrc, out, N);
}